// Round 1
// 396.078 us; speedup vs baseline: 1.0975x; 1.0975x over previous
//
#include <hip/hip_runtime.h>

// Problem constants (B=64, T=512, I=256, H=512)
#define BATCH 64
#define TSTEPS 512
#define IDIM 256
#define HDIM 512
#define MROWS (BATCH * TSTEPS)   // 32768

typedef __attribute__((address_space(1))) const void gvoid;
typedef __attribute__((address_space(3))) void lvoid;

__device__ __forceinline__ void gl2lds16(const void* g, void* l) {
    // async global->LDS, 16B per lane; LDS dest = wave-uniform base + lane*16
    __builtin_amdgcn_global_load_lds((gvoid*)g, (lvoid*)l, 16, 0, 0);
}

// ---------------------------------------------------------------------------
// K0: extract center taps: W1T[i][h] = conv1_w[h][i][1] ([k][n] layout);
//                          W2T[h][j] = conv2_w[j][h][1] ([k][n] layout)
// ---------------------------------------------------------------------------
__global__ void extract_weights(const float* __restrict__ c1w,
                                const float* __restrict__ c2w,
                                float* __restrict__ W1T,
                                float* __restrict__ W2T) {
    int tid = blockIdx.x * 256 + threadIdx.x;
    if (tid < IDIM * HDIM) {
        int i = tid >> 9;          // / 512
        int h = tid & 511;
        W1T[tid] = c1w[(h * IDIM + i) * 3 + 1];
    }
    if (tid < HDIM * HDIM) {
        int h = tid >> 9;
        int j = tid & 511;
        W2T[tid] = c2w[(j * HDIM + h) * 3 + 1];
    }
}

// ---------------------------------------------------------------------------
// K1 dense GEMM — ROUND-4 SHAPE VERBATIM (best measured; LDS-pipe floor).
// C[m][n] = (sum_k A[m][k]*BT[k][n]) [+ bias[n]]
// NUMERICS CONTRACT: each output is ONE sequential fmaf chain, k ascending,
// fp32 — MFMA / split-K / tree reductions flip spikes (R2/R3).
// Now used ONLY for layer 1 (x @ W1T, K=256): x is dense Gaussian, no
// sparsity to exploit. Layer 2 moved to spmm_spikes (spike-sparse, exact).
// ---------------------------------------------------------------------------
#define BM 128
#define BN 128
#define BK 16

__global__ __launch_bounds__(256, 2) void gemm_f32(const float* __restrict__ A,
                                                   const float* __restrict__ BT,
                                                   const float* __restrict__ bias,
                                                   float* __restrict__ C,
                                                   int K, int addBias) {
    __shared__ __align__(16) float As[BK * BM];   // [k][m]  8 KB
    __shared__ __align__(16) float Bs[BK * BN];   // [k][n]  8 KB

    const int N = HDIM;
    int tid  = threadIdx.x;
    int lane = tid & 63;
    int wave = tid >> 6;
    int row0 = blockIdx.x * BM;
    int col0 = blockIdx.y * BN;
    int wm = (wave >> 1) * 64;
    int wn = (wave & 1) * 64;
    int mbase = wm + (lane >> 3) * 8;
    int nbase = wn + (lane & 7) * 8;

    float acc[8][8];
#pragma unroll
    for (int i = 0; i < 8; i++)
#pragma unroll
        for (int j = 0; j < 8; j++) acc[i][j] = 0.0f;

    int ar = tid >> 1;
    int ak = (tid & 1) * 8;
    const float* ap = A + (size_t)(row0 + ar) * K + ak;

    const char* bp = (const char*)(BT + (size_t)(tid >> 5) * N + col0) + (tid & 31) * 16;
    char* bld = (char*)Bs + tid * 16;
    const size_t bRow8 = (size_t)8 * N * sizeof(float);

    for (int k0 = 0; k0 < K; k0 += BK) {
        gl2lds16(bp, bld);
        gl2lds16(bp + bRow8, bld + 4096);
        float4 a0 = *(const float4*)(ap);
        float4 a1 = *(const float4*)(ap + 4);
        ap += BK;
        bp += (size_t)BK * N * sizeof(float);
        As[(ak + 0) * BM + ar] = a0.x;
        As[(ak + 1) * BM + ar] = a0.y;
        As[(ak + 2) * BM + ar] = a0.z;
        As[(ak + 3) * BM + ar] = a0.w;
        As[(ak + 4) * BM + ar] = a1.x;
        As[(ak + 5) * BM + ar] = a1.y;
        As[(ak + 6) * BM + ar] = a1.z;
        As[(ak + 7) * BM + ar] = a1.w;
        __syncthreads();

#pragma unroll
        for (int k = 0; k < BK; k++) {
            float4 av0 = *(const float4*)&As[k * BM + mbase];
            float4 av1 = *(const float4*)&As[k * BM + mbase + 4];
            float4 bv0 = *(const float4*)&Bs[k * BN + nbase];
            float4 bv1 = *(const float4*)&Bs[k * BN + nbase + 4];
            float a8[8] = {av0.x, av0.y, av0.z, av0.w, av1.x, av1.y, av1.z, av1.w};
            float b8[8] = {bv0.x, bv0.y, bv0.z, bv0.w, bv1.x, bv1.y, bv1.z, bv1.w};
#pragma unroll
            for (int i = 0; i < 8; i++)
#pragma unroll
                for (int j = 0; j < 8; j++)
                    acc[i][j] = fmaf(a8[i], b8[j], acc[i][j]);
        }
        __syncthreads();
    }

    float bb[8];
#pragma unroll
    for (int j = 0; j < 8; j++)
        bb[j] = addBias ? bias[col0 + nbase + j] : 0.0f;
#pragma unroll
    for (int i = 0; i < 8; i++) {
        int row = row0 + mbase + i;
        float4* cp = (float4*)&C[(size_t)row * N + col0 + nbase];
        cp[0] = (float4){acc[i][0] + bb[0], acc[i][1] + bb[1],
                         acc[i][2] + bb[2], acc[i][3] + bb[3]};
        cp[1] = (float4){acc[i][4] + bb[4], acc[i][5] + bb[5],
                         acc[i][6] + bb[6], acc[i][7] + bb[7]};
    }
}

// ---------------------------------------------------------------------------
// K2: per-(b,h) LIF scan, ping-pong register prefetch (R7 arithmetic kept
// VERBATIM: m += z; thr = m/th-1; spike = thr>=0; if (thr>0) m -= th).
// NEW: emits spike BITMASKS instead of float s1 (64 MB write -> 2 MB).
// Block = exactly one wave = one 64-h chunk of one batch; __ballot packs the
// 64 spike bits; lane 0 stores the mask word. Bit l of word w for row (b,t)
// corresponds to k = w*64+l — consumed in that order by spmm_spikes.
// ---------------------------------------------------------------------------
__global__ void lif_scan1(const float* __restrict__ z1,
                          unsigned long long* __restrict__ masks,
                          const float* __restrict__ th_p) {
    int gtid = blockIdx.x * blockDim.x + threadIdx.x;   // 0..32767
    int b = gtid >> 9;
    int h = gtid & 511;
    int lane = threadIdx.x & 63;
    int w = h >> 6;                                     // mask word index 0..7
    float th = *th_p;
    const float* zp = z1 + (size_t)b * TSTEPS * HDIM + h;
    unsigned long long* mp = masks + (size_t)b * TSTEPS * 8 + w;
    float m = 0.0f;
    float bufA[16], bufB[16];
#pragma unroll
    for (int i = 0; i < 16; i++) bufA[i] = zp[(size_t)i * HDIM];
    for (int t0 = 0; t0 < TSTEPS; t0 += 32) {
#pragma unroll
        for (int i = 0; i < 16; i++) bufB[i] = zp[(size_t)(t0 + 16 + i) * HDIM];
        {
#pragma unroll
            for (int i = 0; i < 16; i++) {
                m += bufA[i];
                float thr = m / th - 1.0f;
                unsigned long long bal = __ballot(thr >= 0.0f);
                if (lane == 0) mp[(size_t)(t0 + i) * 8] = bal;
                if (thr > 0.0f) m -= th;
            }
        }
        if (t0 + 32 < TSTEPS) {
#pragma unroll
            for (int i = 0; i < 16; i++) bufA[i] = zp[(size_t)(t0 + 32 + i) * HDIM];
        }
        {
#pragma unroll
            for (int i = 0; i < 16; i++) {
                m += bufB[i];
                float thr = m / th - 1.0f;
                unsigned long long bal = __ballot(thr >= 0.0f);
                if (lane == 0) mp[(size_t)(t0 + 16 + i) * 8] = bal;
                if (thr > 0.0f) m -= th;
            }
        }
    }
}

// ---------------------------------------------------------------------------
// K3 (NEW): spike-sparse replacement for s1 @ W2T.
// out[m][:] = sum over active k (ascending) of W2T[k][:].
// BIT-EXACT vs the dense sequential fmaf chain: fmaf(0,w,acc)==acc and
// fmaf(1,w,acc)==rn(acc+w); skipping zeros in k-order preserves every
// rounding step, so spikes cannot flip.
// One wave per output row: 64 lanes x 8 cols = all 512 columns in registers.
// Mask words moved to SGPRs (readfirstlane) -> scalar loop control, zero
// divergence; per active k the wave streams one 2 KB W2T row (L2-resident).
// Expected ~940K active (row,k) pairs -> ~1.9 GB L2 traffic ~ 55-80 us.
// ---------------------------------------------------------------------------
__global__ __launch_bounds__(256) void spmm_spikes(
        const unsigned long long* __restrict__ masks,
        const float* __restrict__ W2T,
        float* __restrict__ C) {
    int lane = threadIdx.x & 63;
    int wave = threadIdx.x >> 6;
    int m = blockIdx.x * 4 + wave;                      // output row
    const unsigned long long* mrow = masks + (size_t)m * 8;

    float4 s0 = {0.0f, 0.0f, 0.0f, 0.0f};
    float4 s1 = {0.0f, 0.0f, 0.0f, 0.0f};

    for (int c = 0; c < 8; c++) {
        unsigned long long mraw = mrow[c];              // wave-uniform (broadcast)
        unsigned int lo = __builtin_amdgcn_readfirstlane((unsigned int)mraw);
        unsigned int hi = __builtin_amdgcn_readfirstlane((unsigned int)(mraw >> 32));
        unsigned long long mk = ((unsigned long long)hi << 32) | lo;   // SGPR pair
        const float* wc = W2T + ((size_t)(c << 6)) * HDIM + lane * 8;
        while (mk) {
            int k = __builtin_ctzll(mk);                // ascending k within word
            mk &= mk - 1;
            const float4* wp = (const float4*)(wc + (size_t)k * HDIM);
            float4 w0 = wp[0];
            float4 w1 = wp[1];
            s0.x += w0.x; s0.y += w0.y; s0.z += w0.z; s0.w += w0.w;
            s1.x += w1.x; s1.y += w1.y; s1.z += w1.z; s1.w += w1.w;
        }
    }

    float4* cp = (float4*)(C + (size_t)m * HDIM + lane * 8);
    cp[0] = s0;
    cp[1] = s1;
}

// ---------------------------------------------------------------------------
// K4: per-(b,j) scan: m2 = (m2 + raw[t]) + bias, spike/reset -> out.
// Ping-pong prefetch (R7 version, verbatim).
// ---------------------------------------------------------------------------
__global__ void lif_scan2(const float* __restrict__ raw,
                          const float* __restrict__ b2,
                          const float* __restrict__ th_p,
                          float* __restrict__ out) {
    int gtid = blockIdx.x * blockDim.x + threadIdx.x;   // 0..32767
    int b = gtid >> 9;
    int j = gtid & 511;
    float th = *th_p;
    float bias = b2[j];
    const float* rp = raw + (size_t)b * TSTEPS * HDIM + j;
    float* op = out + (size_t)b * TSTEPS * HDIM + j;
    float m = 0.0f;
    float bufA[16], bufB[16];
#pragma unroll
    for (int i = 0; i < 16; i++) bufA[i] = rp[(size_t)i * HDIM];
    for (int t0 = 0; t0 < TSTEPS; t0 += 32) {
#pragma unroll
        for (int i = 0; i < 16; i++) bufB[i] = rp[(size_t)(t0 + 16 + i) * HDIM];
        {
            float ss[16];
#pragma unroll
            for (int i = 0; i < 16; i++) {
                m = (m + bufA[i]) + bias;
                float thr = m / th - 1.0f;
                ss[i] = (thr >= 0.0f) ? 1.0f : 0.0f;
                if (thr > 0.0f) m -= th;
            }
#pragma unroll
            for (int i = 0; i < 16; i++) op[(size_t)(t0 + i) * HDIM] = ss[i];
        }
        if (t0 + 32 < TSTEPS) {
#pragma unroll
            for (int i = 0; i < 16; i++) bufA[i] = rp[(size_t)(t0 + 32 + i) * HDIM];
        }
        {
            float ss[16];
#pragma unroll
            for (int i = 0; i < 16; i++) {
                m = (m + bufB[i]) + bias;
                float thr = m / th - 1.0f;
                ss[i] = (thr >= 0.0f) ? 1.0f : 0.0f;
                if (thr > 0.0f) m -= th;
            }
#pragma unroll
            for (int i = 0; i < 16; i++) op[(size_t)(t0 + 16 + i) * HDIM] = ss[i];
        }
    }
}

// ---------------------------------------------------------------------------
extern "C" void kernel_launch(void* const* d_in, const int* in_sizes, int n_in,
                              void* d_out, int out_size, void* d_ws, size_t ws_size,
                              hipStream_t stream) {
    const float* x    = (const float*)d_in[0];   // (64, 512, 256)
    const float* c1w  = (const float*)d_in[1];   // (512, 256, 3)
    const float* c1b  = (const float*)d_in[2];   // (512,)
    const float* c2w  = (const float*)d_in[3];   // (512, 512, 3)
    const float* c2b  = (const float*)d_in[4];   // (512,)
    const float* th1  = (const float*)d_in[5];   // scalar
    const float* th2  = (const float*)d_in[6];   // scalar
    float* out = (float*)d_out;                  // (64, 512, 512)

    // Workspace layout (floats):
    //   W1T  : 131072   (512 KB)  [k=i][n=h]
    //   W2T  : 262144   (1 MB)    [k=h][n=j]
    //   bufA : 16777216 (64 MB)   z1, later z2raw  [m][n]
    //   masks: 32768*8 u64 (2 MB) spike bitmasks   [m][kword]
    float* W1T  = (float*)d_ws;
    float* W2T  = W1T + IDIM * HDIM;
    float* bufA = W2T + HDIM * HDIM;
    unsigned long long* masks = (unsigned long long*)(bufA + (size_t)MROWS * HDIM);

    // K0: weight extraction
    extract_weights<<<(HDIM * HDIM + 255) / 256, 256, 0, stream>>>(c1w, c2w, W1T, W2T);

    // K1: z1 = x @ W1T + b1   (M=32768, K=256, N=512) -> bufA
    {
        dim3 grid(MROWS / BM, HDIM / BN);
        gemm_f32<<<grid, 256, 0, stream>>>(x, W1T, c1b, bufA, IDIM, 1);
    }

    // K2: s1 scan -> spike bitmasks (no float s1 materialization)
    lif_scan1<<<MROWS / 64, 64, 0, stream>>>(bufA, masks, th1);

    // K3: z2raw[m][:] = sum_{k in spikes(m)} W2T[k][:]  (bit-exact sparse)
    spmm_spikes<<<MROWS / 4, 256, 0, stream>>>(masks, W2T, bufA);

    // K4: s2 scan -> out
    lif_scan2<<<MROWS / 64, 64, 0, stream>>>(bufA, c2b, th2, out);
}

// Round 2
// 392.421 us; speedup vs baseline: 1.1077x; 1.0093x over previous
//
#include <hip/hip_runtime.h>

// Problem constants (B=64, T=512, I=256, H=512)
#define BATCH 64
#define TSTEPS 512
#define IDIM 256
#define HDIM 512
#define MROWS (BATCH * TSTEPS)   // 32768
#define KZ HDIM                  // zero-row index in W2T (row 512 == 0.0f)

typedef __attribute__((address_space(1))) const void gvoid;
typedef __attribute__((address_space(3))) void lvoid;

__device__ __forceinline__ void gl2lds16(const void* g, void* l) {
    // async global->LDS, 16B per lane; LDS dest = wave-uniform base + lane*16
    __builtin_amdgcn_global_load_lds((gvoid*)g, (lvoid*)l, 16, 0, 0);
}

// ---------------------------------------------------------------------------
// K0: extract center taps: W1T[i][h] = conv1_w[h][i][1] ([k][n] layout);
//                          W2T[h][j] = conv2_w[j][h][1] ([k][n] layout)
// W2T gets a 513th all-zero row (index KZ=512) used as padding target by the
// sparse layer-2 kernel (adding +0.0f is bit-neutral, same as the dense
// chain's fmaf(0,w,acc) at inactive ks).
// ---------------------------------------------------------------------------
__global__ void extract_weights(const float* __restrict__ c1w,
                                const float* __restrict__ c2w,
                                float* __restrict__ W1T,
                                float* __restrict__ W2T) {
    int tid = blockIdx.x * 256 + threadIdx.x;
    if (tid < IDIM * HDIM) {
        int i = tid >> 9;          // / 512
        int h = tid & 511;
        W1T[tid] = c1w[(h * IDIM + i) * 3 + 1];
    }
    if (tid < HDIM * HDIM) {
        int h = tid >> 9;
        int j = tid & 511;
        W2T[tid] = c2w[(j * HDIM + h) * 3 + 1];
    }
    if (tid < HDIM) {
        W2T[HDIM * HDIM + tid] = 0.0f;   // zero pad row
    }
}

// ---------------------------------------------------------------------------
// K1 dense GEMM — ROUND-4 SHAPE VERBATIM (best measured; LDS-pipe floor).
// C[m][n] = (sum_k A[m][k]*BT[k][n]) [+ bias[n]]
// NUMERICS CONTRACT: each output is ONE sequential fmaf chain, k ascending,
// fp32 — MFMA / split-K / tree reductions flip spikes (R2/R3).
// Used ONLY for layer 1 (x @ W1T, K=256): x is dense Gaussian.
// ---------------------------------------------------------------------------
#define BM 128
#define BN 128
#define BK 16

__global__ __launch_bounds__(256, 2) void gemm_f32(const float* __restrict__ A,
                                                   const float* __restrict__ BT,
                                                   const float* __restrict__ bias,
                                                   float* __restrict__ C,
                                                   int K, int addBias) {
    __shared__ __align__(16) float As[BK * BM];   // [k][m]  8 KB
    __shared__ __align__(16) float Bs[BK * BN];   // [k][n]  8 KB

    const int N = HDIM;
    int tid  = threadIdx.x;
    int lane = tid & 63;
    int wave = tid >> 6;
    int row0 = blockIdx.x * BM;
    int col0 = blockIdx.y * BN;
    int wm = (wave >> 1) * 64;
    int wn = (wave & 1) * 64;
    int mbase = wm + (lane >> 3) * 8;
    int nbase = wn + (lane & 7) * 8;

    float acc[8][8];
#pragma unroll
    for (int i = 0; i < 8; i++)
#pragma unroll
        for (int j = 0; j < 8; j++) acc[i][j] = 0.0f;

    int ar = tid >> 1;
    int ak = (tid & 1) * 8;
    const float* ap = A + (size_t)(row0 + ar) * K + ak;

    const char* bp = (const char*)(BT + (size_t)(tid >> 5) * N + col0) + (tid & 31) * 16;
    char* bld = (char*)Bs + tid * 16;
    const size_t bRow8 = (size_t)8 * N * sizeof(float);

    for (int k0 = 0; k0 < K; k0 += BK) {
        gl2lds16(bp, bld);
        gl2lds16(bp + bRow8, bld + 4096);
        float4 a0 = *(const float4*)(ap);
        float4 a1 = *(const float4*)(ap + 4);
        ap += BK;
        bp += (size_t)BK * N * sizeof(float);
        As[(ak + 0) * BM + ar] = a0.x;
        As[(ak + 1) * BM + ar] = a0.y;
        As[(ak + 2) * BM + ar] = a0.z;
        As[(ak + 3) * BM + ar] = a0.w;
        As[(ak + 4) * BM + ar] = a1.x;
        As[(ak + 5) * BM + ar] = a1.y;
        As[(ak + 6) * BM + ar] = a1.z;
        As[(ak + 7) * BM + ar] = a1.w;
        __syncthreads();

#pragma unroll
        for (int k = 0; k < BK; k++) {
            float4 av0 = *(const float4*)&As[k * BM + mbase];
            float4 av1 = *(const float4*)&As[k * BM + mbase + 4];
            float4 bv0 = *(const float4*)&Bs[k * BN + nbase];
            float4 bv1 = *(const float4*)&Bs[k * BN + nbase + 4];
            float a8[8] = {av0.x, av0.y, av0.z, av0.w, av1.x, av1.y, av1.z, av1.w};
            float b8[8] = {bv0.x, bv0.y, bv0.z, bv0.w, bv1.x, bv1.y, bv1.z, bv1.w};
#pragma unroll
            for (int i = 0; i < 8; i++)
#pragma unroll
                for (int j = 0; j < 8; j++)
                    acc[i][j] = fmaf(a8[i], b8[j], acc[i][j]);
        }
        __syncthreads();
    }

    float bb[8];
#pragma unroll
    for (int j = 0; j < 8; j++)
        bb[j] = addBias ? bias[col0 + nbase + j] : 0.0f;
#pragma unroll
    for (int i = 0; i < 8; i++) {
        int row = row0 + mbase + i;
        float4* cp = (float4*)&C[(size_t)row * N + col0 + nbase];
        cp[0] = (float4){acc[i][0] + bb[0], acc[i][1] + bb[1],
                         acc[i][2] + bb[2], acc[i][3] + bb[3]};
        cp[1] = (float4){acc[i][4] + bb[4], acc[i][5] + bb[5],
                         acc[i][6] + bb[6], acc[i][7] + bb[7]};
    }
}

// ---------------------------------------------------------------------------
// K2: per-(b,h) LIF scan, ping-pong register prefetch (arithmetic VERBATIM:
// m += z; thr = m/th-1; spike = thr>=0; if (thr>0) m -= th).
// Emits spike BITMASKS (__ballot) instead of float s1.
// ---------------------------------------------------------------------------
__global__ void lif_scan1(const float* __restrict__ z1,
                          unsigned long long* __restrict__ masks,
                          const float* __restrict__ th_p) {
    int gtid = blockIdx.x * blockDim.x + threadIdx.x;   // 0..32767
    int b = gtid >> 9;
    int h = gtid & 511;
    int lane = threadIdx.x & 63;
    int w = h >> 6;                                     // mask word index 0..7
    float th = *th_p;
    const float* zp = z1 + (size_t)b * TSTEPS * HDIM + h;
    unsigned long long* mp = masks + (size_t)b * TSTEPS * 8 + w;
    float m = 0.0f;
    float bufA[16], bufB[16];
#pragma unroll
    for (int i = 0; i < 16; i++) bufA[i] = zp[(size_t)i * HDIM];
    for (int t0 = 0; t0 < TSTEPS; t0 += 32) {
#pragma unroll
        for (int i = 0; i < 16; i++) bufB[i] = zp[(size_t)(t0 + 16 + i) * HDIM];
        {
#pragma unroll
            for (int i = 0; i < 16; i++) {
                m += bufA[i];
                float thr = m / th - 1.0f;
                unsigned long long bal = __ballot(thr >= 0.0f);
                if (lane == 0) mp[(size_t)(t0 + i) * 8] = bal;
                if (thr > 0.0f) m -= th;
            }
        }
        if (t0 + 32 < TSTEPS) {
#pragma unroll
            for (int i = 0; i < 16; i++) bufA[i] = zp[(size_t)(t0 + 32 + i) * HDIM];
        }
        {
#pragma unroll
            for (int i = 0; i < 16; i++) {
                m += bufB[i];
                float thr = m / th - 1.0f;
                unsigned long long bal = __ballot(thr >= 0.0f);
                if (lane == 0) mp[(size_t)(t0 + 16 + i) * 8] = bal;
                if (thr > 0.0f) m -= th;
            }
        }
    }
}

// ---------------------------------------------------------------------------
// K3 v2: spike-sparse s1 @ W2T, latency-hiding rewrite.
// Round-1 post-mortem: v1 was latency-bound (VALUBusy 8%, 92 cyc/iter/CU) —
// the dynamic while(mk) loop capped MLP at 2 outstanding loads/wave.
// v2: (a) wave-parallel mask -> u16 k-list in LDS (popcll prefix scatter),
// padded to 4 with KZ (zero row; +0.0f add is bit-neutral);
// (b) double-buffered chunks of 4 ks x 8 float4 loads = 16 outstanding
// loads/wave, accumulate chunk i while chunk i+1 is in flight.
// Per-element accumulation order remains strictly k-ascending -> bit-exact.
// ---------------------------------------------------------------------------
#define LDK(kq_, r0, r1, r2, r3, r4, r5, r6, r7)                          \
    {                                                                      \
        const float* p0_ = W2T + (size_t)(kq_.x) * HDIM + (lane << 3);     \
        const float* p1_ = W2T + (size_t)(kq_.y) * HDIM + (lane << 3);     \
        const float* p2_ = W2T + (size_t)(kq_.z) * HDIM + (lane << 3);     \
        const float* p3_ = W2T + (size_t)(kq_.w) * HDIM + (lane << 3);     \
        r0 = *(const float4*)(p0_);                                        \
        r1 = *(const float4*)(p0_ + 4);                                    \
        r2 = *(const float4*)(p1_);                                        \
        r3 = *(const float4*)(p1_ + 4);                                    \
        r4 = *(const float4*)(p2_);                                        \
        r5 = *(const float4*)(p2_ + 4);                                    \
        r6 = *(const float4*)(p3_);                                        \
        r7 = *(const float4*)(p3_ + 4);                                    \
    }

#define ACC1(x0, x1)                                                       \
    s0.x += x0.x; s0.y += x0.y; s0.z += x0.z; s0.w += x0.w;                \
    s1.x += x1.x; s1.y += x1.y; s1.z += x1.z; s1.w += x1.w;

#define ACC4(r0, r1, r2, r3, r4, r5, r6, r7)                               \
    { ACC1(r0, r1) ACC1(r2, r3) ACC1(r4, r5) ACC1(r6, r7) }

__global__ __launch_bounds__(256) void spmm_spikes(
        const unsigned long long* __restrict__ masks,
        const float* __restrict__ W2T,
        float* __restrict__ C) {
    __shared__ __align__(16) unsigned short klist[4][520];
    int lane = threadIdx.x & 63;
    int wave = threadIdx.x >> 6;
    int m = blockIdx.x * 4 + wave;                      // output row
    const unsigned long long* mrow = masks + (size_t)m * 8;

    // Load all 8 mask words (broadcast, independent -> one latency).
    unsigned long long wv[8];
#pragma unroll
    for (int c = 0; c < 8; c++) wv[c] = mrow[c];

    // Wave-parallel k-list build: lane l owns bit l of each word; its slot is
    // the count of set bits below it. ~50 cycles total, no serial lane-0 loop.
    unsigned short* kl = klist[wave];
    int cnt = 0;
#pragma unroll
    for (int c = 0; c < 8; c++) {
        unsigned long long bal = wv[c];
        int below = (int)__popcll(bal & ((1ull << lane) - 1ull));
        if ((bal >> lane) & 1ull)
            kl[cnt + below] = (unsigned short)((c << 6) | lane);
        cnt += (int)__popcll(bal);
    }
    int pad = (-cnt) & 3;
    if (lane < pad) kl[cnt + lane] = (unsigned short)KZ;
    cnt += pad;
    cnt = __builtin_amdgcn_readfirstlane(cnt);

    float4 s0 = {0.0f, 0.0f, 0.0f, 0.0f};
    float4 s1 = {0.0f, 0.0f, 0.0f, 0.0f};

    int nch = cnt >> 2;
    if (nch > 0) {
        float4 a0, a1, a2, a3, a4, a5, a6, a7;
        float4 b0, b1, b2, b3, b4, b5, b6, b7;
        ushort4 kq = *(const ushort4*)(kl);
        LDK(kq, a0, a1, a2, a3, a4, a5, a6, a7);
        int i = 1;
        for (; i + 1 < nch; i += 2) {
            kq = *(const ushort4*)(kl + (i << 2));
            LDK(kq, b0, b1, b2, b3, b4, b5, b6, b7);
            ACC4(a0, a1, a2, a3, a4, a5, a6, a7);
            kq = *(const ushort4*)(kl + ((i + 1) << 2));
            LDK(kq, a0, a1, a2, a3, a4, a5, a6, a7);
            ACC4(b0, b1, b2, b3, b4, b5, b6, b7);
        }
        if (i < nch) {
            kq = *(const ushort4*)(kl + (i << 2));
            LDK(kq, b0, b1, b2, b3, b4, b5, b6, b7);
            ACC4(a0, a1, a2, a3, a4, a5, a6, a7);
            ACC4(b0, b1, b2, b3, b4, b5, b6, b7);
        } else {
            ACC4(a0, a1, a2, a3, a4, a5, a6, a7);
        }
    }

    float4* cp = (float4*)(C + (size_t)m * HDIM + (lane << 3));
    cp[0] = s0;
    cp[1] = s1;
}

// ---------------------------------------------------------------------------
// K4: per-(b,j) scan: m2 = (m2 + raw[t]) + bias, spike/reset -> out.
// Ping-pong prefetch (verbatim).
// ---------------------------------------------------------------------------
__global__ void lif_scan2(const float* __restrict__ raw,
                          const float* __restrict__ b2,
                          const float* __restrict__ th_p,
                          float* __restrict__ out) {
    int gtid = blockIdx.x * blockDim.x + threadIdx.x;   // 0..32767
    int b = gtid >> 9;
    int j = gtid & 511;
    float th = *th_p;
    float bias = b2[j];
    const float* rp = raw + (size_t)b * TSTEPS * HDIM + j;
    float* op = out + (size_t)b * TSTEPS * HDIM + j;
    float m = 0.0f;
    float bufA[16], bufB[16];
#pragma unroll
    for (int i = 0; i < 16; i++) bufA[i] = rp[(size_t)i * HDIM];
    for (int t0 = 0; t0 < TSTEPS; t0 += 32) {
#pragma unroll
        for (int i = 0; i < 16; i++) bufB[i] = rp[(size_t)(t0 + 16 + i) * HDIM];
        {
            float ss[16];
#pragma unroll
            for (int i = 0; i < 16; i++) {
                m = (m + bufA[i]) + bias;
                float thr = m / th - 1.0f;
                ss[i] = (thr >= 0.0f) ? 1.0f : 0.0f;
                if (thr > 0.0f) m -= th;
            }
#pragma unroll
            for (int i = 0; i < 16; i++) op[(size_t)(t0 + i) * HDIM] = ss[i];
        }
        if (t0 + 32 < TSTEPS) {
#pragma unroll
            for (int i = 0; i < 16; i++) bufA[i] = rp[(size_t)(t0 + 32 + i) * HDIM];
        }
        {
            float ss[16];
#pragma unroll
            for (int i = 0; i < 16; i++) {
                m = (m + bufB[i]) + bias;
                float thr = m / th - 1.0f;
                ss[i] = (thr >= 0.0f) ? 1.0f : 0.0f;
                if (thr > 0.0f) m -= th;
            }
#pragma unroll
            for (int i = 0; i < 16; i++) op[(size_t)(t0 + 16 + i) * HDIM] = ss[i];
        }
    }
}

// ---------------------------------------------------------------------------
extern "C" void kernel_launch(void* const* d_in, const int* in_sizes, int n_in,
                              void* d_out, int out_size, void* d_ws, size_t ws_size,
                              hipStream_t stream) {
    const float* x    = (const float*)d_in[0];   // (64, 512, 256)
    const float* c1w  = (const float*)d_in[1];   // (512, 256, 3)
    const float* c1b  = (const float*)d_in[2];   // (512,)
    const float* c2w  = (const float*)d_in[3];   // (512, 512, 3)
    const float* c2b  = (const float*)d_in[4];   // (512,)
    const float* th1  = (const float*)d_in[5];   // scalar
    const float* th2  = (const float*)d_in[6];   // scalar
    float* out = (float*)d_out;                  // (64, 512, 512)

    // Workspace layout (floats):
    //   W1T  : 131072     (512 KB)  [k=i][n=h]
    //   W2T  : 513*512    (~1 MB)   [k=h][n=j] + zero pad row at k=512
    //   bufA : 16777216   (64 MB)   z1, later z2raw  [m][n]
    //   masks: 32768*8 u64 (2 MB)   spike bitmasks   [m][kword]
    float* W1T  = (float*)d_ws;
    float* W2T  = W1T + IDIM * HDIM;
    float* bufA = W2T + (HDIM + 1) * HDIM;
    unsigned long long* masks = (unsigned long long*)(bufA + (size_t)MROWS * HDIM);

    // K0: weight extraction (+ zero pad row)
    extract_weights<<<(HDIM * HDIM + 255) / 256, 256, 0, stream>>>(c1w, c2w, W1T, W2T);

    // K1: z1 = x @ W1T + b1   (M=32768, K=256, N=512) -> bufA
    {
        dim3 grid(MROWS / BM, HDIM / BN);
        gemm_f32<<<grid, 256, 0, stream>>>(x, W1T, c1b, bufA, IDIM, 1);
    }

    // K2: s1 scan -> spike bitmasks (no float s1 materialization)
    lif_scan1<<<MROWS / 64, 64, 0, stream>>>(bufA, masks, th1);

    // K3: z2raw[m][:] = sum_{k in spikes(m)} W2T[k][:]  (bit-exact sparse)
    spmm_spikes<<<MROWS / 4, 256, 0, stream>>>(masks, W2T, bufA);

    // K4: s2 scan -> out
    lif_scan2<<<MROWS / 64, 64, 0, stream>>>(bufA, c2b, th2, out);
}

// Round 4
// 381.001 us; speedup vs baseline: 1.1409x; 1.0300x over previous
//
#include <hip/hip_runtime.h>

// Problem constants (B=64, T=512, I=256, H=512)
#define BATCH 64
#define TSTEPS 512
#define IDIM 256
#define HDIM 512
#define MROWS (BATCH * TSTEPS)   // 32768
#define KZ HDIM                  // zero-row index in W2T (row 512 == 0.0f)

typedef __attribute__((address_space(1))) const void gvoid;
typedef __attribute__((address_space(3))) void lvoid;

__device__ __forceinline__ void gl2lds16(const void* g, void* l) {
    // async global->LDS, 16B per lane; LDS dest = wave-uniform base + lane*16
    __builtin_amdgcn_global_load_lds((gvoid*)g, (lvoid*)l, 16, 0, 0);
}

// ---------------------------------------------------------------------------
// K0: extract center taps: W1T[i][h] = conv1_w[h][i][1] ([k][n] layout);
//                          W2T[h][j] = conv2_w[j][h][1] ([k][n] layout)
// W2T gets a 513th all-zero row (index KZ=512) used as padding target by the
// sparse layer-2 kernel (adding +0.0f is bit-neutral vs the dense chain's
// fmaf(0,w,acc) at inactive ks — verified absmax 0.0 in rounds 1-2).
// ---------------------------------------------------------------------------
__global__ void extract_weights(const float* __restrict__ c1w,
                                const float* __restrict__ c2w,
                                float* __restrict__ W1T,
                                float* __restrict__ W2T) {
    int tid = blockIdx.x * 256 + threadIdx.x;
    if (tid < IDIM * HDIM) {
        int i = tid >> 9;          // / 512
        int h = tid & 511;
        W1T[tid] = c1w[(h * IDIM + i) * 3 + 1];
    }
    if (tid < HDIM * HDIM) {
        int h = tid >> 9;
        int j = tid & 511;
        W2T[tid] = c2w[(j * HDIM + h) * 3 + 1];
    }
    if (tid < HDIM) {
        W2T[HDIM * HDIM + tid] = 0.0f;   // zero pad row
    }
}

// ---------------------------------------------------------------------------
// K1 dense GEMM — ROUND-4 SHAPE VERBATIM (best measured; LDS-pipe floor).
// NUMERICS CONTRACT: each output is ONE sequential fmaf chain, k ascending.
// Used ONLY for layer 1 (x @ W1T, K=256): x is dense Gaussian.
// ---------------------------------------------------------------------------
#define BM 128
#define BN 128
#define BK 16

__global__ __launch_bounds__(256, 2) void gemm_f32(const float* __restrict__ A,
                                                   const float* __restrict__ BT,
                                                   const float* __restrict__ bias,
                                                   float* __restrict__ C,
                                                   int K, int addBias) {
    __shared__ __align__(16) float As[BK * BM];   // [k][m]  8 KB
    __shared__ __align__(16) float Bs[BK * BN];   // [k][n]  8 KB

    const int N = HDIM;
    int tid  = threadIdx.x;
    int lane = tid & 63;
    int wave = tid >> 6;
    int row0 = blockIdx.x * BM;
    int col0 = blockIdx.y * BN;
    int wm = (wave >> 1) * 64;
    int wn = (wave & 1) * 64;
    int mbase = wm + (lane >> 3) * 8;
    int nbase = wn + (lane & 7) * 8;

    float acc[8][8];
#pragma unroll
    for (int i = 0; i < 8; i++)
#pragma unroll
        for (int j = 0; j < 8; j++) acc[i][j] = 0.0f;

    int ar = tid >> 1;
    int ak = (tid & 1) * 8;
    const float* ap = A + (size_t)(row0 + ar) * K + ak;

    const char* bp = (const char*)(BT + (size_t)(tid >> 5) * N + col0) + (tid & 31) * 16;
    char* bld = (char*)Bs + tid * 16;
    const size_t bRow8 = (size_t)8 * N * sizeof(float);

    for (int k0 = 0; k0 < K; k0 += BK) {
        gl2lds16(bp, bld);
        gl2lds16(bp + bRow8, bld + 4096);
        float4 a0 = *(const float4*)(ap);
        float4 a1 = *(const float4*)(ap + 4);
        ap += BK;
        bp += (size_t)BK * N * sizeof(float);
        As[(ak + 0) * BM + ar] = a0.x;
        As[(ak + 1) * BM + ar] = a0.y;
        As[(ak + 2) * BM + ar] = a0.z;
        As[(ak + 3) * BM + ar] = a0.w;
        As[(ak + 4) * BM + ar] = a1.x;
        As[(ak + 5) * BM + ar] = a1.y;
        As[(ak + 6) * BM + ar] = a1.z;
        As[(ak + 7) * BM + ar] = a1.w;
        __syncthreads();

#pragma unroll
        for (int k = 0; k < BK; k++) {
            float4 av0 = *(const float4*)&As[k * BM + mbase];
            float4 av1 = *(const float4*)&As[k * BM + mbase + 4];
            float4 bv0 = *(const float4*)&Bs[k * BN + nbase];
            float4 bv1 = *(const float4*)&Bs[k * BN + nbase + 4];
            float a8[8] = {av0.x, av0.y, av0.z, av0.w, av1.x, av1.y, av1.z, av1.w};
            float b8[8] = {bv0.x, bv0.y, bv0.z, bv0.w, bv1.x, bv1.y, bv1.z, bv1.w};
#pragma unroll
            for (int i = 0; i < 8; i++)
#pragma unroll
                for (int j = 0; j < 8; j++)
                    acc[i][j] = fmaf(a8[i], b8[j], acc[i][j]);
        }
        __syncthreads();
    }

    float bb[8];
#pragma unroll
    for (int j = 0; j < 8; j++)
        bb[j] = addBias ? bias[col0 + nbase + j] : 0.0f;
#pragma unroll
    for (int i = 0; i < 8; i++) {
        int row = row0 + mbase + i;
        float4* cp = (float4*)&C[(size_t)row * N + col0 + nbase];
        cp[0] = (float4){acc[i][0] + bb[0], acc[i][1] + bb[1],
                         acc[i][2] + bb[2], acc[i][3] + bb[3]};
        cp[1] = (float4){acc[i][4] + bb[4], acc[i][5] + bb[5],
                         acc[i][6] + bb[6], acc[i][7] + bb[7]};
    }
}

// ---------------------------------------------------------------------------
// K2: per-(b,h) LIF scan, ping-pong register prefetch (arithmetic VERBATIM).
// Emits spike BITMASKS (__ballot) instead of float s1.
// ---------------------------------------------------------------------------
__global__ void lif_scan1(const float* __restrict__ z1,
                          unsigned long long* __restrict__ masks,
                          const float* __restrict__ th_p) {
    int gtid = blockIdx.x * blockDim.x + threadIdx.x;   // 0..32767
    int b = gtid >> 9;
    int h = gtid & 511;
    int lane = threadIdx.x & 63;
    int w = h >> 6;                                     // mask word index 0..7
    float th = *th_p;
    const float* zp = z1 + (size_t)b * TSTEPS * HDIM + h;
    unsigned long long* mp = masks + (size_t)b * TSTEPS * 8 + w;
    float m = 0.0f;
    float bufA[16], bufB[16];
#pragma unroll
    for (int i = 0; i < 16; i++) bufA[i] = zp[(size_t)i * HDIM];
    for (int t0 = 0; t0 < TSTEPS; t0 += 32) {
#pragma unroll
        for (int i = 0; i < 16; i++) bufB[i] = zp[(size_t)(t0 + 16 + i) * HDIM];
        {
#pragma unroll
            for (int i = 0; i < 16; i++) {
                m += bufA[i];
                float thr = m / th - 1.0f;
                unsigned long long bal = __ballot(thr >= 0.0f);
                if (lane == 0) mp[(size_t)(t0 + i) * 8] = bal;
                if (thr > 0.0f) m -= th;
            }
        }
        if (t0 + 32 < TSTEPS) {
#pragma unroll
            for (int i = 0; i < 16; i++) bufA[i] = zp[(size_t)(t0 + 32 + i) * HDIM];
        }
        {
#pragma unroll
            for (int i = 0; i < 16; i++) {
                m += bufB[i];
                float thr = m / th - 1.0f;
                unsigned long long bal = __ballot(thr >= 0.0f);
                if (lane == 0) mp[(size_t)(t0 + 16 + i) * 8] = bal;
                if (thr > 0.0f) m -= th;
            }
        }
    }
}

// ---------------------------------------------------------------------------
// K3 v4: spike-sparse s1 @ W2T via global_load_lds double-buffered staging.
// Round-3 post-mortem: asm-tuple register pipeline crashed; replaced with
// the PROVEN gl2lds + counted-vmcnt + sched_barrier template (same builtins
// as the working GEMM above).
// One wave per row. Chunks of CH=4 W2T rows staged into LDS (8 gl2lds x 1KB,
// linear layout, m104-safe). Steady state: issue chunk c+1 (8 loads), wait
// vmcnt(8) (chunk c staged), ds_read + accumulate chunk c in ascending k
// order -> bit-exact (KZ pad adds +0.0f, validated rounds 1-2).
// ---------------------------------------------------------------------------
#define CH 4

__global__ __launch_bounds__(64, 1) void spmm_spikes(
        const unsigned long long* __restrict__ masks,
        const float* __restrict__ W2T,
        float* __restrict__ C) {
    __shared__ __align__(16) float stage[2][CH][HDIM];   // 16 KB
    __shared__ __align__(16) unsigned short klist[520];  // ~1 KB
    int lane = threadIdx.x;                              // 64-thr block = 1 wave
    int m = blockIdx.x;                                  // output row
    const unsigned long long* mrow = masks + (size_t)m * 8;

    // Load all 8 mask words (broadcast, independent -> one latency).
    unsigned long long wv[8];
#pragma unroll
    for (int c = 0; c < 8; c++) wv[c] = mrow[c];

    // Wave-parallel k-list build (rounds 1-2 verified): lane l owns bit l of
    // each word; slot = count of set bits below. Pad to multiple of CH with KZ.
    int cnt = 0;
#pragma unroll
    for (int c = 0; c < 8; c++) {
        unsigned long long bal = wv[c];
        int below = (int)__popcll(bal & ((1ull << lane) - 1ull));
        if ((bal >> lane) & 1ull)
            klist[cnt + below] = (unsigned short)((c << 6) | lane);
        cnt += (int)__popcll(bal);
    }
    int pad = (-cnt) & (CH - 1);
    if (lane < pad) klist[cnt + lane] = (unsigned short)KZ;
    cnt += pad;
    cnt = __builtin_amdgcn_readfirstlane(cnt);
    int nch = cnt >> 2;

    float4 s0 = {0.0f, 0.0f, 0.0f, 0.0f};
    float4 s1 = {0.0f, 0.0f, 0.0f, 0.0f};

    // Stage chunk ci into stage[buf]: 4 rows x 2KB, each row = 2 x gl2lds16
    // (1KB each: 64 lanes x 16B, linear). Global src per-lane; LDS dst
    // follows the working GEMM convention (base + lane*16B per lane).
#define STAGE(buf, ci)                                                      \
    {                                                                       \
        ushort4 kq_ = *(const ushort4*)(klist + ((ci) << 2));               \
        const float* g0_ = W2T + (size_t)kq_.x * HDIM + (lane << 2);        \
        const float* g1_ = W2T + (size_t)kq_.y * HDIM + (lane << 2);        \
        const float* g2_ = W2T + (size_t)kq_.z * HDIM + (lane << 2);        \
        const float* g3_ = W2T + (size_t)kq_.w * HDIM + (lane << 2);        \
        float* l_ = &stage[buf][0][0] + (lane << 2);                        \
        gl2lds16(g0_,       l_);                                            \
        gl2lds16(g0_ + 256, l_ + 256);                                      \
        gl2lds16(g1_,       l_ + 512);                                      \
        gl2lds16(g1_ + 256, l_ + 768);                                      \
        gl2lds16(g2_,       l_ + 1024);                                     \
        gl2lds16(g2_ + 256, l_ + 1280);                                     \
        gl2lds16(g3_,       l_ + 1536);                                     \
        gl2lds16(g3_ + 256, l_ + 1792);                                     \
    }

    if (nch > 0) {
        // Drain mask loads so vmcnt counts only staging loads.
        asm volatile("s_waitcnt vmcnt(0)" ::: "memory");
        __builtin_amdgcn_sched_barrier(0);
        STAGE(0, 0);
        int cur = 0;
        for (int c = 0; c < nch; c++) {
            if (c + 1 < nch) {
                STAGE(cur ^ 1, c + 1);
                __builtin_amdgcn_sched_barrier(0);
                asm volatile("s_waitcnt vmcnt(8)" ::: "memory");   // chunk c staged
            } else {
                __builtin_amdgcn_sched_barrier(0);
                asm volatile("s_waitcnt vmcnt(0)" ::: "memory");
            }
            __builtin_amdgcn_sched_barrier(0);   // rule #18: pin ds_read below wait
            const float* base = &stage[cur][0][0] + (lane << 3);
#pragma unroll
            for (int q = 0; q < CH; q++) {
                float4 w0 = *(const float4*)(base + q * HDIM);
                float4 w1 = *(const float4*)(base + q * HDIM + 4);
                s0.x += w0.x; s0.y += w0.y; s0.z += w0.z; s0.w += w0.w;
                s1.x += w1.x; s1.y += w1.y; s1.z += w1.z; s1.w += w1.w;
            }
            __builtin_amdgcn_sched_barrier(0);   // keep consume inside its phase
            cur ^= 1;
        }
    }
#undef STAGE

    float4* cp = (float4*)(C + (size_t)m * HDIM + (lane << 3));
    cp[0] = s0;
    cp[1] = s1;
}

// ---------------------------------------------------------------------------
// K4: per-(b,j) scan: m2 = (m2 + raw[t]) + bias, spike/reset -> out.
// Ping-pong prefetch (verbatim).
// ---------------------------------------------------------------------------
__global__ void lif_scan2(const float* __restrict__ raw,
                          const float* __restrict__ b2,
                          const float* __restrict__ th_p,
                          float* __restrict__ out) {
    int gtid = blockIdx.x * blockDim.x + threadIdx.x;   // 0..32767
    int b = gtid >> 9;
    int j = gtid & 511;
    float th = *th_p;
    float bias = b2[j];
    const float* rp = raw + (size_t)b * TSTEPS * HDIM + j;
    float* op = out + (size_t)b * TSTEPS * HDIM + j;
    float m = 0.0f;
    float bufA[16], bufB[16];
#pragma unroll
    for (int i = 0; i < 16; i++) bufA[i] = rp[(size_t)i * HDIM];
    for (int t0 = 0; t0 < TSTEPS; t0 += 32) {
#pragma unroll
        for (int i = 0; i < 16; i++) bufB[i] = rp[(size_t)(t0 + 16 + i) * HDIM];
        {
            float ss[16];
#pragma unroll
            for (int i = 0; i < 16; i++) {
                m = (m + bufA[i]) + bias;
                float thr = m / th - 1.0f;
                ss[i] = (thr >= 0.0f) ? 1.0f : 0.0f;
                if (thr > 0.0f) m -= th;
            }
#pragma unroll
            for (int i = 0; i < 16; i++) op[(size_t)(t0 + i) * HDIM] = ss[i];
        }
        if (t0 + 32 < TSTEPS) {
#pragma unroll
            for (int i = 0; i < 16; i++) bufA[i] = rp[(size_t)(t0 + 32 + i) * HDIM];
        }
        {
            float ss[16];
#pragma unroll
            for (int i = 0; i < 16; i++) {
                m = (m + bufB[i]) + bias;
                float thr = m / th - 1.0f;
                ss[i] = (thr >= 0.0f) ? 1.0f : 0.0f;
                if (thr > 0.0f) m -= th;
            }
#pragma unroll
            for (int i = 0; i < 16; i++) op[(size_t)(t0 + 16 + i) * HDIM] = ss[i];
        }
    }
}

// ---------------------------------------------------------------------------
extern "C" void kernel_launch(void* const* d_in, const int* in_sizes, int n_in,
                              void* d_out, int out_size, void* d_ws, size_t ws_size,
                              hipStream_t stream) {
    const float* x    = (const float*)d_in[0];   // (64, 512, 256)
    const float* c1w  = (const float*)d_in[1];   // (512, 256, 3)
    const float* c1b  = (const float*)d_in[2];   // (512,)
    const float* c2w  = (const float*)d_in[3];   // (512, 512, 3)
    const float* c2b  = (const float*)d_in[4];   // (512,)
    const float* th1  = (const float*)d_in[5];   // scalar
    const float* th2  = (const float*)d_in[6];   // scalar
    float* out = (float*)d_out;                  // (64, 512, 512)

    // Workspace layout (floats):
    //   W1T  : 131072     (512 KB)  [k=i][n=h]
    //   W2T  : 513*512    (~1 MB)   [k=h][n=j] + zero pad row at k=512
    //   bufA : 16777216   (64 MB)   z1, later z2raw  [m][n]
    //   masks: 32768*8 u64 (2 MB)   spike bitmasks   [m][kword]
    float* W1T  = (float*)d_ws;
    float* W2T  = W1T + IDIM * HDIM;
    float* bufA = W2T + (HDIM + 1) * HDIM;
    unsigned long long* masks = (unsigned long long*)(bufA + (size_t)MROWS * HDIM);

    // K0: weight extraction (+ zero pad row)
    extract_weights<<<(HDIM * HDIM + 255) / 256, 256, 0, stream>>>(c1w, c2w, W1T, W2T);

    // K1: z1 = x @ W1T + b1   (M=32768, K=256, N=512) -> bufA
    {
        dim3 grid(MROWS / BM, HDIM / BN);
        gemm_f32<<<grid, 256, 0, stream>>>(x, W1T, c1b, bufA, IDIM, 1);
    }

    // K2: s1 scan -> spike bitmasks (no float s1 materialization)
    lif_scan1<<<MROWS / 64, 64, 0, stream>>>(bufA, masks, th1);

    // K3: z2raw[m][:] = sum_{k in spikes(m)} W2T[k][:]  (bit-exact sparse)
    spmm_spikes<<<MROWS, 64, 0, stream>>>(masks, W2T, bufA);

    // K4: s2 scan -> out
    lif_scan2<<<MROWS / 64, 64, 0, stream>>>(bufA, c2b, th2, out);
}